// Round 4
// baseline (1811.311 us; speedup 1.0000x reference)
//
#include <hip/hip_runtime.h>
#include <stdint.h>

#define N_SIZE 4096
#define N_STEPS 512
#define WROW 8192
#define THRESH 10.0f
#define CCAP 12

#define WST_BYTES ((size_t)(N_SIZE + 1) * N_SIZE * 4)   // + zero pad row
#define SMEM_OFF  WST_BYTES
#define SLST_OFF  (WST_BYTES + (size_t)N_SIZE * 4)
#define FULL_WS   (SLST_OFF + (size_t)(N_SIZE + 17) * 4)

#define F4E(v, j) ((j) == 0 ? (v).x : (j) == 1 ? (v).y : (j) == 2 ? (v).z : (v).w)
#define ADD4(a, b) { (a).x += (b).x; (a).y += (b).y; (a).z += (b).z; (a).w += (b).w; }

// ---------------- transpose: WsT[s][o] = W[o*8192 + 4096 + s] ----------------
__global__ __launch_bounds__(256) void k_transpose(const float* __restrict__ W,
                                                   float* __restrict__ WsT) {
    __shared__ float tile[32][33];
    const int bs = blockIdx.x * 32;
    const int bo = blockIdx.y * 32;
    const int tx = threadIdx.x;
    const int ty = threadIdx.y;
#pragma unroll
    for (int j = 0; j < 4; ++j)
        tile[ty + j * 8][tx] = W[(size_t)(bo + ty + j * 8) * WROW + N_SIZE + bs + tx];
    __syncthreads();
#pragma unroll
    for (int j = 0; j < 4; ++j)
        WsT[(size_t)(bs + ty + j * 8) * N_SIZE + bo + tx] = tile[tx][ty + j * 8];
}

// ---------------- zero the pad row (every launch; ws is poisoned once) ------
__global__ __launch_bounds__(256) void k_zero_row(float* __restrict__ WsT) {
    WsT[(size_t)N_SIZE * N_SIZE + blockIdx.x * 256 + threadIdx.x] = 0.f;
}

// ---------------- GEMM: C[t][o] = sum_k x[t][k] * W[o][k], split-K=2 --------
#define BM 64
#define BN 128
#define BK 16
#define KHALF (N_SIZE / 2)
#define ALD 68
#define BLD 132

__global__ __launch_bounds__(128) void k_gemm(const float* __restrict__ x,
                                              const float* __restrict__ W,
                                              float* __restrict__ dst0,
                                              float* __restrict__ dst1) {
    __shared__ float As[BK][ALD];
    __shared__ float Bs[BK][BLD];
    const int tid = threadIdx.x;
    const int bm = blockIdx.y * BM;
    const int bn = blockIdx.x * BN;
    const int kb0 = blockIdx.z * KHALF;
    float* dst = blockIdx.z ? dst1 : dst0;

    const int m0 = (tid >> 4) << 3;
    const int n0 = (tid & 15) << 2;
    const int ar = tid >> 2;
    const int ac = (tid & 3) << 2;
    const float* Ap = &x[(size_t)(bm + ar) * N_SIZE + kb0 + ac];
    const float* Bp = &W[(size_t)(bn + ar) * WROW + kb0 + ac];

    float4 pa0 = *(const float4*)&Ap[0];
    float4 pa1 = *(const float4*)&Ap[(size_t)32 * N_SIZE];
    float4 pb0 = *(const float4*)&Bp[0];
    float4 pb1 = *(const float4*)&Bp[(size_t)32 * WROW];
    float4 pb2 = *(const float4*)&Bp[(size_t)64 * WROW];
    float4 pb3 = *(const float4*)&Bp[(size_t)96 * WROW];

    float acc[8][8];
#pragma unroll
    for (int i = 0; i < 8; ++i)
#pragma unroll
        for (int j = 0; j < 8; ++j) acc[i][j] = 0.f;

    const int nkt = KHALF / BK;
    for (int kt = 0; kt < nkt; ++kt) {
        __syncthreads();
#pragma unroll
        for (int j = 0; j < 4; ++j) {
            As[ac + j][ar]      = F4E(pa0, j);
            As[ac + j][ar + 32] = F4E(pa1, j);
            Bs[ac + j][ar]      = F4E(pb0, j);
            Bs[ac + j][ar + 32] = F4E(pb1, j);
            Bs[ac + j][ar + 64] = F4E(pb2, j);
            Bs[ac + j][ar + 96] = F4E(pb3, j);
        }
        __syncthreads();
        if (kt + 1 < nkt) {
            const float* Ap2 = Ap + (size_t)(kt + 1) * BK;
            const float* Bp2 = Bp + (size_t)(kt + 1) * BK;
            pa0 = *(const float4*)&Ap2[0];
            pa1 = *(const float4*)&Ap2[(size_t)32 * N_SIZE];
            pb0 = *(const float4*)&Bp2[0];
            pb1 = *(const float4*)&Bp2[(size_t)32 * WROW];
            pb2 = *(const float4*)&Bp2[(size_t)64 * WROW];
            pb3 = *(const float4*)&Bp2[(size_t)96 * WROW];
        }
#pragma unroll
        for (int k = 0; k < BK; ++k) {
            const float4 a0 = *(const float4*)&As[k][m0];
            const float4 a1 = *(const float4*)&As[k][m0 + 4];
            const float4 b0 = *(const float4*)&Bs[k][n0];
            const float4 b1 = *(const float4*)&Bs[k][n0 + 64];
            const float av[8] = {a0.x, a0.y, a0.z, a0.w, a1.x, a1.y, a1.z, a1.w};
            const float bv[8] = {b0.x, b0.y, b0.z, b0.w, b1.x, b1.y, b1.z, b1.w};
#pragma unroll
            for (int i = 0; i < 8; ++i)
#pragma unroll
                for (int j = 0; j < 8; ++j)
                    acc[i][j] = fmaf(av[i], bv[j], acc[i][j]);
        }
    }
#pragma unroll
    for (int i = 0; i < 8; ++i) {
        float* cp = &dst[(size_t)(bm + m0 + i) * N_SIZE + bn];
        const float4 o0 = {acc[i][0], acc[i][1], acc[i][2], acc[i][3]};
        const float4 o1 = {acc[i][4], acc[i][5], acc[i][6], acc[i][7]};
        *(float4*)&cp[n0] = o0;
        *(float4*)&cp[n0 + 64] = o1;
    }
}

__global__ __launch_bounds__(256) void k_reduce(float* __restrict__ acc,
                                                const float* __restrict__ part) {
    const size_t i = ((size_t)blockIdx.x * 256 + threadIdx.x) * 4;
    const float4 a = *(const float4*)&acc[i];
    const float4 b = *(const float4*)&part[i];
    const float4 r = {a.x + b.x, a.y + b.y, a.z + b.z, a.w + b.w};
    *(float4*)&acc[i] = r;
}

// ---------------- single-WG scan, fully-batched gather ----------------
// 512 threads * 8 neurons. Per step: one 12-column chunk gather (one lgkm
// round for indices, one vmcnt round for 24 saddr float4 loads, zero-pad row
// makes it branch/mask-free), threshold, sorted compaction (2 barriers).
// Runs as two 256-step dispatches; state (mem, list) handed off via ws.
#define GCOL(k)                                                               \
    const int s##k = __builtin_amdgcn_readfirstlane(lst[n0 + k]);             \
    const float* p##k = &WsT[(size_t)s##k * N_SIZE + base];

__global__ __launch_bounds__(512) void k_scanF(const float* __restrict__ WsT,
                                               float* __restrict__ spk_out,
                                               float* __restrict__ mem_out,
                                               float* __restrict__ smem,
                                               int* __restrict__ slst,
                                               int t0, int t1) {
    __shared__ int lst[N_SIZE + 16];
    __shared__ int wcnt[8];
    const int tid = threadIdx.x;
    const int wave = tid >> 6;
    const int lane = tid & 63;
    const int base = tid << 3;          // neurons base..base+7
    const unsigned long long below = (lane == 0) ? 0ULL : (~0ULL >> (64 - lane));

    float4 m0 = {0.f, 0.f, 0.f, 0.f}, m1 = {0.f, 0.f, 0.f, 0.f};
    int tot = 0;

    if (t0 != 0) {
        m0 = *(const float4*)&smem[base];
        m1 = *(const float4*)&smem[base + 4];
        for (int i = tid; i < N_SIZE + 16; i += 512) lst[i] = slst[i];
        tot = slst[N_SIZE + 16];
        __syncthreads();
    }

    float4 cn0 = *(const float4*)&mem_out[(size_t)t0 * N_SIZE + base];
    float4 cn1 = *(const float4*)&mem_out[(size_t)t0 * N_SIZE + base + 4];

    for (int t = t0; t < t1; ++t) {
        float4 c0 = cn0, c1 = cn1;

        // ---- gather: 12 columns fully in flight per chunk ----
        for (int n0 = 0; n0 < tot; n0 += CCAP) {
            GCOL(0)  GCOL(1)  GCOL(2)  GCOL(3)  GCOL(4)  GCOL(5)
            GCOL(6)  GCOL(7)  GCOL(8)  GCOL(9)  GCOL(10) GCOL(11)
            const float4 a0 = *(const float4*)&p0[0],  b0v = *(const float4*)&p0[4];
            const float4 a1 = *(const float4*)&p1[0],  b1v = *(const float4*)&p1[4];
            const float4 a2 = *(const float4*)&p2[0],  b2v = *(const float4*)&p2[4];
            const float4 a3 = *(const float4*)&p3[0],  b3v = *(const float4*)&p3[4];
            const float4 a4 = *(const float4*)&p4[0],  b4v = *(const float4*)&p4[4];
            const float4 a5 = *(const float4*)&p5[0],  b5v = *(const float4*)&p5[4];
            const float4 a6 = *(const float4*)&p6[0],  b6v = *(const float4*)&p6[4];
            const float4 a7 = *(const float4*)&p7[0],  b7v = *(const float4*)&p7[4];
            const float4 a8 = *(const float4*)&p8[0],  b8v = *(const float4*)&p8[4];
            const float4 a9 = *(const float4*)&p9[0],  b9v = *(const float4*)&p9[4];
            const float4 aA = *(const float4*)&p10[0], bAv = *(const float4*)&p10[4];
            const float4 aB = *(const float4*)&p11[0], bBv = *(const float4*)&p11[4];
            ADD4(c0, a0) ADD4(c1, b0v)
            ADD4(c0, a1) ADD4(c1, b1v)
            ADD4(c0, a2) ADD4(c1, b2v)
            ADD4(c0, a3) ADD4(c1, b3v)
            ADD4(c0, a4) ADD4(c1, b4v)
            ADD4(c0, a5) ADD4(c1, b5v)
            ADD4(c0, a6) ADD4(c1, b6v)
            ADD4(c0, a7) ADD4(c1, b7v)
            ADD4(c0, a8) ADD4(c1, b8v)
            ADD4(c0, a9) ADD4(c1, b9v)
            ADD4(c0, aA) ADD4(c1, bAv)
            ADD4(c0, aB) ADD4(c1, bBv)
        }

        // ---- membrane update, threshold ----
        ADD4(m0, c0) ADD4(m1, c1)
        const bool s0b = m0.x > THRESH, s1b = m0.y > THRESH;
        const bool s2b = m0.z > THRESH, s3b = m0.w > THRESH;
        const bool s4b = m1.x > THRESH, s5b = m1.y > THRESH;
        const bool s6b = m1.z > THRESH, s7b = m1.w > THRESH;
        m0.x -= s0b ? THRESH : 0.f;  m0.y -= s1b ? THRESH : 0.f;
        m0.z -= s2b ? THRESH : 0.f;  m0.w -= s3b ? THRESH : 0.f;
        m1.x -= s4b ? THRESH : 0.f;  m1.y -= s5b ? THRESH : 0.f;
        m1.z -= s6b ? THRESH : 0.f;  m1.w -= s7b ? THRESH : 0.f;

        // ---- ballots + per-wave count ----
        const unsigned long long B0 = __ballot(s0b), B1 = __ballot(s1b);
        const unsigned long long B2 = __ballot(s2b), B3 = __ballot(s3b);
        const unsigned long long B4 = __ballot(s4b), B5 = __ballot(s5b);
        const unsigned long long B6 = __ballot(s6b), B7 = __ballot(s7b);
        const int pre = __popcll(B0 & below) + __popcll(B1 & below) +
                        __popcll(B2 & below) + __popcll(B3 & below) +
                        __popcll(B4 & below) + __popcll(B5 & below) +
                        __popcll(B6 & below) + __popcll(B7 & below);
        if (lane == 0)
            wcnt[wave] = __popcll(B0) + __popcll(B1) + __popcll(B2) + __popcll(B3) +
                         __popcll(B4) + __popcll(B5) + __popcll(B6) + __popcll(B7);

        // ---- outputs + next-row prefetch (off critical path) ----
        const float4 sp0 = {s0b ? 1.f : 0.f, s1b ? 1.f : 0.f,
                            s2b ? 1.f : 0.f, s3b ? 1.f : 0.f};
        const float4 sp1 = {s4b ? 1.f : 0.f, s5b ? 1.f : 0.f,
                            s6b ? 1.f : 0.f, s7b ? 1.f : 0.f};
        float* srow = &spk_out[(size_t)t * N_SIZE + base];
        float* mrow = &mem_out[(size_t)t * N_SIZE + base];
        *(float4*)&srow[0] = sp0;
        *(float4*)&srow[4] = sp1;
        *(float4*)&mrow[0] = m0;
        *(float4*)&mrow[4] = m1;
        const int tn = (t + 1 < N_STEPS) ? (t + 1) : t;
        cn0 = *(const float4*)&mem_out[(size_t)tn * N_SIZE + base];
        cn1 = *(const float4*)&mem_out[(size_t)tn * N_SIZE + base + 4];

        __syncthreads();   // bar1: wcnt visible; all gather reads of lst done

        int woff = 0, tt = 0;
#pragma unroll
        for (int w = 0; w < 8; ++w) {
            const int cw = wcnt[w];
            if (w < wave) woff += cw;
            tt += cw;
        }
        int off = woff + pre;
        if (s0b) lst[off++] = base + 0;
        if (s1b) lst[off++] = base + 1;
        if (s2b) lst[off++] = base + 2;
        if (s3b) lst[off++] = base + 3;
        if (s4b) lst[off++] = base + 4;
        if (s5b) lst[off++] = base + 5;
        if (s6b) lst[off++] = base + 6;
        if (s7b) lst[off++] = base + 7;
        if (tid < 16) lst[tt + tid] = N_SIZE;   // pad -> zero row
        __syncthreads();   // bar2: list ready

        tot = tt;
    }

    if (t1 < N_STEPS) {   // hand off state to second dispatch
        *(float4*)&smem[base] = m0;
        *(float4*)&smem[base + 4] = m1;
        for (int i = tid; i < N_SIZE + 16; i += 512) slst[i] = lst[i];
        if (tid == 0) slst[N_SIZE + 16] = tot;
    }
}

// ---------------- fallback: single-WG scan (no/partial ws) ----------------
template <int USE_WST>
__global__ __launch_bounds__(1024) void k_scan1(const float* __restrict__ WsT,
                                                const float* __restrict__ W,
                                                float* __restrict__ spk_out,
                                                float* __restrict__ mem_out) {
    __shared__ int lists[2][N_SIZE];
    __shared__ int wcnt[16];
    const int tid = threadIdx.x;
    const int wave = tid >> 6;
    const int lane = tid & 63;
    const int base = tid << 2;
    const unsigned long long below = (lane == 0) ? 0ULL : (~0ULL >> (64 - lane));

    float4 mem = {0.f, 0.f, 0.f, 0.f};
    int cnt = 0, cur = 0;
    for (int t = 0; t < N_STEPS; ++t) {
        float* mrow = &mem_out[(size_t)t * N_SIZE + base];
        float4 c = *(const float4*)mrow;
        const int* lstp = lists[cur];
        for (int i = 0; i < cnt; ++i) {
            const int s = lstp[i];
            float4 w0;
            if (USE_WST) {
                w0 = *(const float4*)&WsT[(size_t)s * N_SIZE + base];
            } else {
                w0.x = W[(size_t)(base + 0) * WROW + N_SIZE + s];
                w0.y = W[(size_t)(base + 1) * WROW + N_SIZE + s];
                w0.z = W[(size_t)(base + 2) * WROW + N_SIZE + s];
                w0.w = W[(size_t)(base + 3) * WROW + N_SIZE + s];
            }
            ADD4(c, w0)
        }
        ADD4(mem, c)
        const bool s0 = mem.x > THRESH, s1 = mem.y > THRESH;
        const bool s2 = mem.z > THRESH, s3 = mem.w > THRESH;
        mem.x -= s0 ? THRESH : 0.f;  mem.y -= s1 ? THRESH : 0.f;
        mem.z -= s2 ? THRESH : 0.f;  mem.w -= s3 ? THRESH : 0.f;
        const float4 spkv = {s0 ? 1.f : 0.f, s1 ? 1.f : 0.f,
                             s2 ? 1.f : 0.f, s3 ? 1.f : 0.f};
        *(float4*)&spk_out[(size_t)t * N_SIZE + base] = spkv;
        *(float4*)mrow = mem;
        const unsigned long long b0 = __ballot(s0), b1 = __ballot(s1);
        const unsigned long long b2 = __ballot(s2), b3 = __ballot(s3);
        const int pre = __popcll(b0 & below) + __popcll(b1 & below) +
                        __popcll(b2 & below) + __popcll(b3 & below);
        if (lane == 0)
            wcnt[wave] = __popcll(b0) + __popcll(b1) + __popcll(b2) + __popcll(b3);
        __syncthreads();
        int woff = 0, total = 0;
#pragma unroll
        for (int wv = 0; wv < 16; ++wv) {
            const int cw = wcnt[wv];
            if (wv < wave) woff += cw;
            total += cw;
        }
        int* nxt = lists[cur ^ 1];
        int off = woff + pre;
        if (s0) nxt[off++] = base;
        if (s1) nxt[off++] = base + 1;
        if (s2) nxt[off++] = base + 2;
        if (s3) nxt[off++] = base + 3;
        __syncthreads();
        cnt = total;
        cur ^= 1;
    }
}

extern "C" void kernel_launch(void* const* d_in, const int* in_sizes, int n_in,
                              void* d_out, int out_size, void* d_ws, size_t ws_size,
                              hipStream_t stream) {
    const float* x = (const float*)d_in[0];
    const float* W = (const float*)d_in[1];
    float* spk_out = (float*)d_out;
    float* mem_out = spk_out + (size_t)N_STEPS * N_SIZE;
    float* WsT = (float*)d_ws;
    float* smem = (float*)((char*)d_ws + SMEM_OFF);
    int* slst = (int*)((char*)d_ws + SLST_OFF);
    const bool full = ws_size >= FULL_WS;
    const bool use_wst = ws_size >= (size_t)N_SIZE * N_SIZE * 4;

    if (full) {
        k_zero_row<<<16, 256, 0, stream>>>(WsT);
        k_transpose<<<dim3(N_SIZE / 32, N_SIZE / 32), dim3(32, 8), 0, stream>>>(W, WsT);
    } else if (use_wst) {
        k_transpose<<<dim3(N_SIZE / 32, N_SIZE / 32), dim3(32, 8), 0, stream>>>(W, WsT);
    }

    k_gemm<<<dim3(N_SIZE / BN, N_STEPS / BM, 2), 128, 0, stream>>>(x, W, mem_out, spk_out);
    k_reduce<<<(N_STEPS * N_SIZE) / (256 * 4), 256, 0, stream>>>(mem_out, spk_out);

    if (full) {
        k_scanF<<<1, 512, 0, stream>>>(WsT, spk_out, mem_out, smem, slst, 0, 256);
        k_scanF<<<1, 512, 0, stream>>>(WsT, spk_out, mem_out, smem, slst, 256, 512);
    } else if (use_wst) {
        k_scan1<1><<<1, 1024, 0, stream>>>(WsT, W, spk_out, mem_out);
    } else {
        k_scan1<0><<<1, 1024, 0, stream>>>(WsT, W, spk_out, mem_out);
    }
}